// Round 10
// baseline (319.125 us; speedup 1.0000x reference)
//
#include <hip/hip_runtime.h>

#define SEQ 512
#define BATCH 8192
#define LOG2E  1.44269504088896340736f
#define LOG2E2 2.88539008177792681472f   // 2*log2(e)

typedef _Float16 f16x8 __attribute__((ext_vector_type(8)));
typedef float    f32x4 __attribute__((ext_vector_type(4)));

__device__ __forceinline__ float fexp2(float x) { return __builtin_amdgcn_exp2f(x); }
__device__ __forceinline__ float frcp(float x)  { return __builtin_amdgcn_rcpf(x); }

// Layer-split MFMA LSTM: block = 2 waves x 16 batch elements.
//   wave0 (w1=0): h1[t+1] = LSTM0(h1[t], x[t+1])   — self-contained recurrence
//   wave1 (w1=1): h2[t]   = LSTM1(h1[t], h2[t-1])  — h1 via LDS mailbox
// Each wave: z(40+8dummy rows) = W·v as 3 tiles x 3 mfma_f32_16x16x32_f16
// (hi·hi, lo·hi, hi·lo — r8-verified split precision), C = prescaled bias.
// D layout: lane (q,e) owns pairs {4T+q} (4 gates in 4 acc regs, lane-local
// c/h update). B k-map (k=8q+j):
//   wave0: j0,1 = x (q=0 only);  j2+T = h1[4T+q]  (producer==consumer, regs)
//   wave1: j0..2 = h1[4j+q] (mailbox);  j3+T = h2[4T+q] (regs)
// Mailbox: [buf][T][lane] u32 = f16(h1hi) | f16(h1lo)<<16; wave0 lane (q,e)
// writes exactly the slots wave1 lane (q,e) reads — no cross-lane traffic,
// no bank conflicts. Double-buffered, ONE __syncthreads per step.
__global__ __launch_bounds__(128) void lstm2_fc_mfma(
    const float* __restrict__ x,
    const float* __restrict__ w_ih0, const float* __restrict__ w_hh0,
    const float* __restrict__ b_ih0, const float* __restrict__ b_hh0,
    const float* __restrict__ w_ih1, const float* __restrict__ w_hh1,
    const float* __restrict__ b_ih1, const float* __restrict__ b_hh1,
    const float* __restrict__ fc_w, const float* __restrict__ fc_b,
    float* __restrict__ out)
{
    __shared__ unsigned mbox[2][3][64];
    __shared__ float hfc[16][10];

    const int tid  = threadIdx.x;
    const int w1   = tid >> 6;           // 0: layer-0 wave, 1: layer-1 wave
    const int lane = tid & 63;
    const int e    = lane & 15;          // elem column / A-row-in-tile
    const int q    = lane >> 4;          // K-chunk; D row-quad
    const int Eb   = blockIdx.x * 16;
    const bool qz  = (q == 0);

    // ---- A fragments hi/lo (prescaled) + C bias, per wave ----
    f16x8 ahi[3], alo[3];
    f32x4 cb[3];
    #pragma unroll
    for (int T = 0; T < 3; ++T) {
        const int Pa = 4 * T + (e >> 2), Ga = e & 3;   // row e -> pair/gate
        const bool realA = (Pa < 10);
        const int wr = Ga * 10 + (realA ? Pa : 0);
        const float m = ((Ga == 2) ? LOG2E2 : -LOG2E) * (realA ? 1.0f : 0.0f);
        #pragma unroll
        for (int j = 0; j < 8; ++j) {
            float w = 0.0f;
            if (!w1) {                                 // L0: v = [x(2); h1(10)]
                if (j < 2)      { if (q == 0) w = w_ih0[wr * 2 + j]; }
                else if (j < 5) { const int u = 4 * (j - 2) + q;
                                  if (u < 10) w = w_hh0[wr * 10 + u]; }
            } else {                                   // L1: v = [h1(10); h2(10)]
                if (j < 3)      { const int u = 4 * j + q;
                                  if (u < 10) w = w_ih1[wr * 10 + u]; }
                else if (j < 6) { const int u = 4 * (j - 3) + q;
                                  if (u < 10) w = w_hh1[wr * 10 + u]; }
            }
            const float wm = m * w;
            const _Float16 wh = (_Float16)wm;
            ahi[T][j] = wh;
            alo[T][j] = (_Float16)(wm - (float)wh);
        }
        const int Pc = 4 * T + q;                      // C/D pair for this lane
        const bool realC = (Pc < 10);
        #pragma unroll
        for (int r = 0; r < 4; ++r) {
            const int wrc = r * 10 + (realC ? Pc : 0);
            const float mc = ((r == 2) ? LOG2E2 : -LOG2E) * (realC ? 1.0f : 0.0f);
            cb[T][r] = mc * (w1 ? (b_ih1[wrc] + b_hh1[wrc])
                                : (b_ih0[wrc] + b_hh0[wrc]));
        }
    }

    // ---- B state registers ----
    f16x8 Bh, Bl;
    #pragma unroll
    for (int j = 0; j < 8; ++j) { Bh[j] = (_Float16)0.f; Bl[j] = (_Float16)0.f; }

    // ---- wave0: x prefetch regs ----
    const float* xe = x + ((size_t)Eb + e) * 2;
    float2 x1v{0.f, 0.f};
    float2 xr0[8], xr1[8];
    if (!w1) {
        const float2 x0 = *(const float2*)xe;
        x1v = *(const float2*)(xe + (size_t)1 * BATCH * 2);
        #pragma unroll
        for (int i = 0; i < 8; ++i) xr0[i] = *(const float2*)(xe + (size_t)(2 + i) * BATCH * 2);
        #pragma unroll
        for (int i = 0; i < 8; ++i) xr1[i] = *(const float2*)(xe + (size_t)(10 + i) * BATCH * 2);
        const _Float16 xa = (_Float16)x0.x, xb2 = (_Float16)x0.y;
        Bh[0] = qz ? xa : (_Float16)0.f;
        Bh[1] = qz ? xb2 : (_Float16)0.f;
        Bl[0] = qz ? (_Float16)(x0.x - (float)xa) : (_Float16)0.f;
        Bl[1] = qz ? (_Float16)(x0.y - (float)xb2) : (_Float16)0.f;
    }

    float cst[3] = {0.f, 0.f, 0.f};
    float hT[3];

#define ACT(T, ZZ)                                                             \
    {                                                                          \
        const float d0 = 1.0f + fexp2(ZZ[0]);                                  \
        const float d1 = 1.0f + fexp2(ZZ[1]);                                  \
        const float d2 = 1.0f + fexp2(ZZ[2]);                                  \
        const float d3 = 1.0f + fexp2(ZZ[3]);                                  \
        const float m1 = d0 * d1, m2 = d2 * d3;                                \
        const float pq_ = frcp(m1 * m2);                                       \
        const float pif = m2 * pq_, pgo = m1 * pq_;                            \
        const float si = d1 * pif, sf = d0 * pif;                              \
        const float tg = fmaf(-2.0f, d3 * pgo, 1.0f);                          \
        sO[T] = d2 * pgo;                                                      \
        cst[T] = fmaf(sf, cst[T], si * tg);                                    \
        eC[T] = 1.0f + fexp2(LOG2E2 * cst[T]);                                 \
    }

#define MFMA9()                                                                \
        f32x4 z0 = __builtin_amdgcn_mfma_f32_16x16x32_f16(ahi[0], Bh, cb[0], 0, 0, 0); \
        f32x4 z1 = __builtin_amdgcn_mfma_f32_16x16x32_f16(ahi[1], Bh, cb[1], 0, 0, 0); \
        f32x4 z2 = __builtin_amdgcn_mfma_f32_16x16x32_f16(ahi[2], Bh, cb[2], 0, 0, 0); \
        z0 = __builtin_amdgcn_mfma_f32_16x16x32_f16(alo[0], Bh, z0, 0, 0, 0);  \
        z1 = __builtin_amdgcn_mfma_f32_16x16x32_f16(alo[1], Bh, z1, 0, 0, 0);  \
        z2 = __builtin_amdgcn_mfma_f32_16x16x32_f16(alo[2], Bh, z2, 0, 0, 0);  \
        z0 = __builtin_amdgcn_mfma_f32_16x16x32_f16(ahi[0], Bl, z0, 0, 0, 0);  \
        z1 = __builtin_amdgcn_mfma_f32_16x16x32_f16(ahi[1], Bl, z1, 0, 0, 0);  \
        z2 = __builtin_amdgcn_mfma_f32_16x16x32_f16(ahi[2], Bl, z2, 0, 0, 0);  \
        float eC[3], sO[3];                                                    \
        ACT(0, z0) ACT(1, z1) ACT(2, z2)                                       \
        const float p01 = frcp(eC[0] * eC[1]);                                 \
        const float p2  = frcp(eC[2]);                                         \
        hT[0] = sO[0] * fmaf(-2.0f, eC[1] * p01, 1.0f);                        \
        hT[1] = sO[1] * fmaf(-2.0f, eC[0] * p01, 1.0f);                        \
        hT[2] = sO[2] * fmaf(-2.0f, p2, 1.0f);

    // wave0 step: consume Bh/Bl, produce h1 -> regs j2..4 + mailbox MBUF,
    // insert XIN = next x.
#define STEP0(XIN, MBUF)                                                       \
    {                                                                          \
        MFMA9()                                                                \
        _Pragma("unroll")                                                      \
        for (int T = 0; T < 3; ++T) {                                          \
            const _Float16 hh = (_Float16)hT[T];                               \
            const _Float16 hl = (_Float16)(hT[T] - (float)hh);                 \
            Bh[2 + T] = hh;                                                    \
            Bl[2 + T] = hl;                                                    \
            mbox[MBUF][T][lane] =                                              \
                (unsigned)__builtin_bit_cast(unsigned short, hh) |             \
                ((unsigned)__builtin_bit_cast(unsigned short, hl) << 16);      \
        }                                                                      \
        const _Float16 xa = (_Float16)(XIN).x, xb2 = (_Float16)(XIN).y;        \
        Bh[0] = qz ? xa : (_Float16)0.f;                                       \
        Bh[1] = qz ? xb2 : (_Float16)0.f;                                      \
        Bl[0] = qz ? (_Float16)((XIN).x - (float)xa) : (_Float16)0.f;          \
        Bl[1] = qz ? (_Float16)((XIN).y - (float)xb2) : (_Float16)0.f;         \
    }

    // wave1 step: read h1 from mailbox MBUF into j0..2, compute, h2 -> j3..5.
#define STEP1(MBUF)                                                            \
    {                                                                          \
        _Pragma("unroll")                                                      \
        for (int T = 0; T < 3; ++T) {                                          \
            const unsigned mv = mbox[MBUF][T][lane];                           \
            Bh[T] = __builtin_bit_cast(_Float16, (unsigned short)(mv & 0xffffu)); \
            Bl[T] = __builtin_bit_cast(_Float16, (unsigned short)(mv >> 16));  \
        }                                                                      \
        MFMA9()                                                                \
        _Pragma("unroll")                                                      \
        for (int T = 0; T < 3; ++T) {                                          \
            const _Float16 hh = (_Float16)hT[T];                               \
            Bh[3 + T] = hh;                                                    \
            Bl[3 + T] = (_Float16)(hT[T] - (float)hh);                         \
        }                                                                      \
    }

    // ---- prologue (L=0): wave0 computes h1[0] from x[0], h=0 -> mbox[0] ----
    if (!w1) STEP0(x1v, 0)
    __syncthreads();

    // ---- main: L = 16cc+s+1 in [1, 512] ----
    for (int cc = 0; cc < 32; ++cc) {
        #pragma unroll
        for (int s = 0; s < 16; ++s) {
            const int wb = (s + 1) & 1;      // wave0 writes buf[L&1]
            const int rb = s & 1;            // wave1 reads buf[(L-1)&1]
            if (!w1) {
                if (cc < 31 || s < 15) {     // skip L=512 (h1[512] unneeded)
                    const float2 xin = (s < 8) ? xr0[s & 7] : xr1[s & 7];
                    STEP0(xin, wb)
                }
            } else {
                STEP1(rb)
            }
            __syncthreads();
            if (!w1 && s == 7) {             // reload chunk for next cc
                #pragma unroll
                for (int i = 0; i < 8; ++i) {
                    int ti = 16 * cc + 18 + i; if (ti > 511) ti = 511;
                    xr0[i] = *(const float2*)(xe + (size_t)ti * BATCH * 2);
                }
            }
            if (!w1 && s == 15) {
                #pragma unroll
                for (int i = 0; i < 8; ++i) {
                    int ti = 16 * cc + 26 + i; if (ti > 511) ti = 511;
                    xr1[i] = *(const float2*)(xe + (size_t)ti * BATCH * 2);
                }
            }
        }
    }
#undef STEP0
#undef STEP1
#undef MFMA9
#undef ACT

    // ---- FC from wave1's h2[511] (lane (q,e) owns L1 units q,4+q,8+q) ----
    if (w1) {
        hfc[e][q]     = hT[0];
        hfc[e][4 + q] = hT[1];
        if (q < 2) hfc[e][8 + q] = hT[2];
    }
    __syncthreads();
    if (tid < 32) {
        const int ee = tid >> 1, jj = tid & 1;
        float acc = fc_b[jj];
        #pragma unroll
        for (int u = 0; u < 10; ++u)
            acc = fmaf(fc_w[jj * 10 + u], hfc[ee][u], acc);
        out[((size_t)Eb + ee) * 2 + jj] = acc;
    }
}

extern "C" void kernel_launch(void* const* d_in, const int* in_sizes, int n_in,
                              void* d_out, int out_size, void* d_ws, size_t ws_size,
                              hipStream_t stream) {
    const float* x     = (const float*)d_in[0];
    const float* w_ih0 = (const float*)d_in[1];
    const float* w_hh0 = (const float*)d_in[2];
    const float* b_ih0 = (const float*)d_in[3];
    const float* b_hh0 = (const float*)d_in[4];
    const float* w_ih1 = (const float*)d_in[5];
    const float* w_hh1 = (const float*)d_in[6];
    const float* b_ih1 = (const float*)d_in[7];
    const float* b_hh1 = (const float*)d_in[8];
    const float* fc_w  = (const float*)d_in[9];
    const float* fc_b  = (const float*)d_in[10];
    float* out = (float*)d_out;

    const int threads = 128;                  // 2 waves: layer0 + layer1
    const int blocks  = BATCH / 16;           // 512 blocks -> 1024 waves
    lstm2_fc_mfma<<<blocks, threads, 0, stream>>>(
        x, w_ih0, w_hh0, b_ih0, b_hh0,
        w_ih1, w_hh1, b_ih1, b_hh1, fc_w, fc_b, out);
}

// Round 11
// 256.096 us; speedup vs baseline: 1.2461x; 1.2461x over previous
//
#include <hip/hip_runtime.h>

#define SEQ 512
#define BATCH 8192
#define LOG2E  1.44269504088896340736f
#define LOG2E2 2.88539008177792681472f   // 2*log2(e)

typedef _Float16 f16x8 __attribute__((ext_vector_type(8)));
typedef float    f32x4 __attribute__((ext_vector_type(4)));
typedef unsigned u32x4 __attribute__((ext_vector_type(4)));

__device__ __forceinline__ float fexp2(float x) { return __builtin_amdgcn_exp2f(x); }
__device__ __forceinline__ float frcp(float x)  { return __builtin_amdgcn_rcpf(x); }
__device__ __forceinline__ unsigned pkf16(_Float16 a, _Float16 b) {
    return (unsigned)__builtin_bit_cast(unsigned short, a) |
           ((unsigned)__builtin_bit_cast(unsigned short, b) << 16);
}

// Layer-split MFMA LSTM, K=8-batched windows (1 barrier per 8 steps).
//   wave0: h1[t] = LSTM0(h1[t-1], x[t])  — all-register recurrence
//   wave1: h2[t] = LSTM1(h1[t], h2[t-1]) — h1 via 8-slot LDS mailbox
// Per wave-step: z(40+8 dummy rows) = W·v as 3 tiles x 2 MFMA (16x16x32 f16):
// z = Whi·B + Wlo·B + bias(C).  h carried hi-f16 only (lo dropped; r8's 26x
// error headroom covers it); x carried EXACTLY: x_lo occupies spare B slots
// j5,j6 with duplicated w_ih0 columns in A (free precision, no extra MFMA).
// D layout: lane (q,e) owns pairs {4T+q}, 4 gates in 4 acc regs (lane-local).
// B k-map (k=8q+j):
//   wave0: j0,1 = x_hi (q0); j2..4 = h1[4(j-2)+q]; j5,6 = x_lo (q0); j7 = 0
//   wave1: j0..2 = h1[4j+q]; j3..5 = h2[4(j-3)+q]; j6,7 = 0
// Mailbox: [buf][slot][2][64] dwords; wave0 lane (q,e) writes exactly what
// wave1 lane (q,e) reads (pk(h1[q],h1[4+q]), pk(h1[8+q],0)) — conflict-free.
// Reads prefetched one step ahead; x-chunk reloads issued at window START so
// the barrier's waitcnt-drain finds them complete (r10's hidden cost).
__global__ __launch_bounds__(128) void lstm2_fc_mfma(
    const float* __restrict__ x,
    const float* __restrict__ w_ih0, const float* __restrict__ w_hh0,
    const float* __restrict__ b_ih0, const float* __restrict__ b_hh0,
    const float* __restrict__ w_ih1, const float* __restrict__ w_hh1,
    const float* __restrict__ b_ih1, const float* __restrict__ b_hh1,
    const float* __restrict__ fc_w, const float* __restrict__ fc_b,
    float* __restrict__ out)
{
    __shared__ unsigned mbox[2][8][2][64];
    __shared__ float hfc[16][10];

    const int tid  = threadIdx.x;
    const int w1   = tid >> 6;           // 0: layer-0 wave, 1: layer-1 wave
    const int lane = tid & 63;
    const int e    = lane & 15;          // elem column / A-row-in-tile
    const int q    = lane >> 4;          // K-chunk; D row-quad
    const int Eb   = blockIdx.x * 16;
    const bool qz  = (q == 0);

    // ---- A fragments hi/lo (prescaled) + C bias ----
    f16x8 ahi[3], alo[3];
    f32x4 cb[3];
    #pragma unroll
    for (int T = 0; T < 3; ++T) {
        const int Pa = 4 * T + (e >> 2), Ga = e & 3;   // A row e -> pair/gate
        const bool realA = (Pa < 10);
        const int wr = Ga * 10 + (realA ? Pa : 0);
        const float m = ((Ga == 2) ? LOG2E2 : -LOG2E) * (realA ? 1.0f : 0.0f);
        #pragma unroll
        for (int j = 0; j < 8; ++j) {
            float w = 0.0f;
            if (!w1) {               // L0: [x_hi(2,q0); h1(j2..4); x_lo(2,q0)]
                if (j < 2)                    { if (q == 0) w = w_ih0[wr * 2 + j]; }
                else if (j < 5)               { const int u = 4 * (j - 2) + q;
                                                if (u < 10) w = w_hh0[wr * 10 + u]; }
                else if (j == 5 || j == 6)    { if (q == 0) w = w_ih0[wr * 2 + (j - 5)]; }
            } else {                 // L1: [h1(j0..2); h2(j3..5)]
                if (j < 3)      { const int u = 4 * j + q;
                                  if (u < 10) w = w_ih1[wr * 10 + u]; }
                else if (j < 6) { const int u = 4 * (j - 3) + q;
                                  if (u < 10) w = w_hh1[wr * 10 + u]; }
            }
            const float wm = m * w;
            const _Float16 wh = (_Float16)wm;
            ahi[T][j] = wh;
            alo[T][j] = (_Float16)(wm - (float)wh);
        }
        const int Pc = 4 * T + q;                      // C/D pair for this lane
        const bool realC = (Pc < 10);
        #pragma unroll
        for (int r = 0; r < 4; ++r) {
            const int wrc = r * 10 + (realC ? Pc : 0);
            const float mc = ((r == 2) ? LOG2E2 : -LOG2E) * (realC ? 1.0f : 0.0f);
            cb[T][r] = mc * (w1 ? (b_ih1[wrc] + b_hh1[wrc])
                                : (b_ih0[wrc] + b_hh0[wrc]));
        }
    }

    // ---- state ----
    unsigned d0 = 0u, d1 = 0u, d2 = 0u, d3 = 0u;       // B dwords
    float cst[3] = {0.f, 0.f, 0.f};
    float hT[3]  = {0.f, 0.f, 0.f};
    _Float16 h2s0 = (_Float16)0.f, h2s1 = (_Float16)0.f, h2s2 = (_Float16)0.f;

    // ---- wave0: x prefetch ----
    const float* xe = x + ((size_t)Eb + e) * 2;
    float2 xcP[8], xcA[8], xcB[8];
    if (!w1) {
        const float2 x0v = *(const float2*)xe;
        #pragma unroll
        for (int s = 0; s < 8; ++s) xcP[s] = *(const float2*)(xe + (size_t)(1 + s) * BATCH * 2);
        #pragma unroll
        for (int s = 0; s < 8; ++s) xcA[s] = *(const float2*)(xe + (size_t)(9 + s) * BATCH * 2);
        #pragma unroll
        for (int s = 0; s < 8; ++s) xcB[s] = *(const float2*)(xe + (size_t)(17 + s) * BATCH * 2);
        // init B with x[0] (h = 0)
        const _Float16 xa = (_Float16)x0v.x, xb = (_Float16)x0v.y;
        d0 = qz ? pkf16(xa, xb) : 0u;
        d2 = qz ? pkf16((_Float16)0.f, (_Float16)(x0v.x - (float)xa)) : 0u;
        d3 = qz ? pkf16((_Float16)(x0v.y - (float)xb), (_Float16)0.f) : 0u;
    }

#define ACT(T, ZZ)                                                             \
    {                                                                          \
        const float a0 = 1.0f + fexp2(ZZ[0]);                                  \
        const float a1 = 1.0f + fexp2(ZZ[1]);                                  \
        const float a2 = 1.0f + fexp2(ZZ[2]);                                  \
        const float a3 = 1.0f + fexp2(ZZ[3]);                                  \
        const float m1 = a0 * a1, m2 = a2 * a3;                                \
        const float pq_ = frcp(m1 * m2);                                       \
        const float pif = m2 * pq_, pgo = m1 * pq_;                            \
        const float si = a1 * pif, sf = a0 * pif;                              \
        const float tg = fmaf(-2.0f, a3 * pgo, 1.0f);                          \
        sO[T] = a2 * pgo;                                                      \
        cst[T] = fmaf(sf, cst[T], si * tg);                                    \
        eC[T] = 1.0f + fexp2(LOG2E2 * cst[T]);                                 \
    }

#define MFMA_ACT()                                                             \
        const f16x8 Bv = __builtin_bit_cast(f16x8, (u32x4){d0, d1, d2, d3});   \
        f32x4 z0 = __builtin_amdgcn_mfma_f32_16x16x32_f16(ahi[0], Bv, cb[0], 0, 0, 0); \
        f32x4 z1 = __builtin_amdgcn_mfma_f32_16x16x32_f16(ahi[1], Bv, cb[1], 0, 0, 0); \
        f32x4 z2 = __builtin_amdgcn_mfma_f32_16x16x32_f16(ahi[2], Bv, cb[2], 0, 0, 0); \
        z0 = __builtin_amdgcn_mfma_f32_16x16x32_f16(alo[0], Bv, z0, 0, 0, 0);  \
        z1 = __builtin_amdgcn_mfma_f32_16x16x32_f16(alo[1], Bv, z1, 0, 0, 0);  \
        z2 = __builtin_amdgcn_mfma_f32_16x16x32_f16(alo[2], Bv, z2, 0, 0, 0);  \
        float eC[3], sO[3];                                                    \
        ACT(0, z0) ACT(1, z1) ACT(2, z2)                                       \
        const float p01 = frcp(eC[0] * eC[1]);                                 \
        const float p2  = frcp(eC[2]);                                         \
        hT[0] = sO[0] * fmaf(-2.0f, eC[1] * p01, 1.0f);                        \
        hT[1] = sO[1] * fmaf(-2.0f, eC[0] * p01, 1.0f);                        \
        hT[2] = sO[2] * fmaf(-2.0f, p2, 1.0f);

    // wave0 step: produce h1 -> B slots j2..4 + mailbox[WBUF][S]; insert XH.
#define STEP0(XH, S, WBUF)                                                     \
    {                                                                          \
        MFMA_ACT()                                                             \
        const _Float16 h0f = (_Float16)hT[0];                                  \
        const _Float16 h1f = (_Float16)hT[1];                                  \
        const _Float16 h2f = (_Float16)hT[2];                                  \
        d1 = pkf16(h0f, h1f);                                                  \
        mbox[WBUF][S][0][lane] = d1;                                           \
        mbox[WBUF][S][1][lane] = pkf16(h2f, (_Float16)0.f);                    \
        const _Float16 xa = (_Float16)(XH).x, xb = (_Float16)(XH).y;           \
        d0 = qz ? pkf16(xa, xb) : 0u;                                          \
        d2 = pkf16(h2f, qz ? (_Float16)((XH).x - (float)xa) : (_Float16)0.f);  \
        d3 = qz ? pkf16((_Float16)((XH).y - (float)xb), (_Float16)0.f) : 0u;   \
    }

    // wave1 step: assemble B from mailbox dwords (MA,MB) + own h2 regs.
#define STEP1(MA, MB)                                                          \
    {                                                                          \
        d0 = (MA);                                                             \
        d1 = ((MB) & 0xffffu) |                                                \
             ((unsigned)__builtin_bit_cast(unsigned short, h2s0) << 16);       \
        d2 = pkf16(h2s1, h2s2);                                                \
        d3 = 0u;                                                               \
        MFMA_ACT()                                                             \
        h2s0 = (_Float16)hT[0];                                                \
        h2s1 = (_Float16)hT[1];                                                \
        h2s2 = (_Float16)hT[2];                                                \
    }

    // wave1 window: 8 steps reading mbox[RB], reads prefetched 1 step ahead.
#define WIN1(RB)                                                               \
    {                                                                          \
        unsigned mA = mbox[RB][0][0][lane], mB = mbox[RB][0][1][lane];         \
        _Pragma("unroll")                                                      \
        for (int s = 0; s < 8; ++s) {                                          \
            unsigned nA = 0u, nB = 0u;                                         \
            if (s < 7) { nA = mbox[RB][s + 1][0][lane];                        \
                         nB = mbox[RB][s + 1][1][lane]; }                      \
            STEP1(mA, mB)                                                      \
            mA = nA; mB = nB;                                                  \
        }                                                                      \
    }

    // ---- prologue window: wave0 h1[0..7] -> buf0 ----
    if (!w1) {
        #pragma unroll
        for (int s = 0; s < 8; ++s) STEP0(xcP[s], s, 0)
    }
    __syncthreads();

    // ---- 64 windows: window i: wave0 -> h1[8(i+1)+s] into buf[(i+1)&1]
    //                            wave1 -> h2[8i+s]     from buf[i&1]
    for (int m = 0; m < 32; ++m) {
        // window 2m
        if (!w1) {
            if (m > 0) {                       // reload xcB = CH(2m+1)
                #pragma unroll
                for (int s = 0; s < 8; ++s) {
                    int t = 8 * (2 * m + 2) + 1 + s; if (t > 511) t = 511;
                    xcB[s] = *(const float2*)(xe + (size_t)t * BATCH * 2);
                }
            }
            #pragma unroll
            for (int s = 0; s < 8; ++s) STEP0(xcA[s], s, 1)
        } else {
            WIN1(0)
        }
        __syncthreads();
        // window 2m+1
        if (!w1) {
            {                                  // reload xcA = CH(2m+2)
                #pragma unroll
                for (int s = 0; s < 8; ++s) {
                    int t = 8 * (2 * m + 3) + 1 + s; if (t > 511) t = 511;
                    xcA[s] = *(const float2*)(xe + (size_t)t * BATCH * 2);
                }
            }
            if (m < 31) {                      // window 63: wave0 idle
                #pragma unroll
                for (int s = 0; s < 8; ++s) STEP0(xcB[s], s, 0)
            }
        } else {
            WIN1(1)
        }
        __syncthreads();
    }
#undef WIN1
#undef STEP1
#undef STEP0
#undef MFMA_ACT
#undef ACT

    // ---- FC from wave1's h2[511] (lane (q,e): L1 units q, 4+q, 8+q(q<2)) ----
    if (w1) {
        hfc[e][q]     = hT[0];
        hfc[e][4 + q] = hT[1];
        if (q < 2) hfc[e][8 + q] = hT[2];
    }
    __syncthreads();
    if (tid < 32) {
        const int ee = tid >> 1, jj = tid & 1;
        float acc = fc_b[jj];
        #pragma unroll
        for (int u = 0; u < 10; ++u)
            acc = fmaf(fc_w[jj * 10 + u], hfc[ee][u], acc);
        out[((size_t)Eb + ee) * 2 + jj] = acc;
    }
}

extern "C" void kernel_launch(void* const* d_in, const int* in_sizes, int n_in,
                              void* d_out, int out_size, void* d_ws, size_t ws_size,
                              hipStream_t stream) {
    const float* x     = (const float*)d_in[0];
    const float* w_ih0 = (const float*)d_in[1];
    const float* w_hh0 = (const float*)d_in[2];
    const float* b_ih0 = (const float*)d_in[3];
    const float* b_hh0 = (const float*)d_in[4];
    const float* w_ih1 = (const float*)d_in[5];
    const float* w_hh1 = (const float*)d_in[6];
    const float* b_ih1 = (const float*)d_in[7];
    const float* b_hh1 = (const float*)d_in[8];
    const float* fc_w  = (const float*)d_in[9];
    const float* fc_b  = (const float*)d_in[10];
    float* out = (float*)d_out;

    const int threads = 128;                  // 2 waves: layer0 + layer1
    const int blocks  = BATCH / 16;           // 512 blocks -> 1024 waves
    lstm2_fc_mfma<<<blocks, threads, 0, stream>>>(
        x, w_ih0, w_hh0, b_ih0, b_hh0,
        w_ih1, w_hh1, b_ih1, b_hh1, fc_w, fc_b, out);
}